// Round 3
// baseline (3083.227 us; speedup 1.0000x reference)
//
#include <hip/hip_runtime.h>
#include <math.h>

#define BATCH 128
#define SLEN  8000
#define HID   64
#define CHUNK 64                  // steps per fc flush; 8000 = 125 * 64
#define NCHUNK (SLEN / CHUNK)     // 125
#define ROWSTRIDE 68              // floats; keeps b128 row reads conflict-free

__device__ __forceinline__ float fast_exp2(float x) { return __builtin_amdgcn_exp2f(x); }
__device__ __forceinline__ float fast_rcp(float x)  { return __builtin_amdgcn_rcpf(x); }

__device__ __forceinline__ float bcast_lane(float v, int lane) {
    return __int_as_float(__builtin_amdgcn_readlane(__float_as_int(v), lane));
}

// tanh(x) = sign(x) * (e - 1)/(e + 1), e = 2^(2|x|*log2 e)   (UNCHANGED - bitwise)
__device__ __forceinline__ float tanh_fast(float x) {
    float ax = fabsf(x);
    float z  = fminf(ax * 2.8853900817779268f, 30.0f);
    float e  = fast_exp2(z);
    float r  = (e - 1.0f) * fast_rcp(e + 1.0f);
    return x < 0.0f ? -r : r;
}

__device__ __forceinline__ float sigmoid_fast(float x) {
    float z = fminf(fmaxf(-x * 1.4426950408889634f, -60.0f), 60.0f);
    float e = fast_exp2(z);
    return fast_rcp(1.0f + e);
}

// 4-wave split-K: wave w owns j = w (mod 4)  == the original acc[w] chain.
// Per step each wave: 16 readlanes + 16 chained FMAs -> partial to LDS ->
// lgkmcnt(0) + s_barrier -> all waves combine (p0+p1)+(p2+p3) -> tanh -> h
// replicated per wave. Every fp op and order matches the 1-wave kernel
// exactly -> bitwise-identical output.
__global__ __launch_bounds__(256) void rnn_splitk4_kernel(
    const float* __restrict__ x,      // [B, S]
    const float* __restrict__ W_ih,   // [H, 1]
    const float* __restrict__ b_ih,   // [H]
    const float* __restrict__ W_hh,   // [H, H]
    const float* __restrict__ b_hh,   // [H]
    const float* __restrict__ fc_w,   // [2, H]
    const float* __restrict__ fc_b,   // [2]
    float* __restrict__ out)          // [B]
{
    __shared__ float part[2][4][HID];           // [parity][wave][i] partial sums
    __shared__ float hbuf[CHUNK * ROWSTRIDE];   // h history for the fc head
    __shared__ float rowred_n[HID];
    __shared__ float rowred_d[HID];

    const int tid  = threadIdx.x;
    const int lane = tid & 63;
    const int wv   = __builtin_amdgcn_readfirstlane(tid >> 6);   // 0..3, SGPR
    const int b    = blockIdx.x;
    const float* xrow = x + (size_t)b * SLEN;

    // Lane i of wave w holds w_sub[k] = W_hh[i][4k+w]  (16 VGPRs)
    float w_sub[16];
    #pragma unroll
    for (int k = 0; k < 16; ++k)
        w_sub[k] = W_hh[lane * HID + 4 * k + wv];

    const float wih  = W_ih[lane];            // used by wave 0 only (acc0 seed)
    const float bias = b_ih[lane] + b_hh[lane];
    const float fcb0 = fc_b[0], fcb1 = fc_b[1];

    float h = 0.0f;                 // replicated hidden state: lane i = h[i], per wave
    float num = 0.0f, den = 0.0f;   // fc accumulators (lanes 0..15 active)

    float xv_next = 0.0f;
    if (wv == 0) xv_next = xrow[lane];        // chunk 0's x values

    #pragma unroll 1
    for (int c = 0; c < NCHUNK; ++c) {
        float xcur = xv_next;
        if (wv == 0) {
            int nidx = (c + 1 < NCHUNK) ? (c + 1) * CHUNK + lane : lane;
            xv_next = xrow[nidx];             // raw barriers never drain vmcnt
        }

        #pragma unroll 4
        for (int r = 0; r < CHUNK; ++r) {
            // acc[wv] chain, exact original order: seed, then j = 4k+wv ascending
            float acc;
            if (wv == 0) {
                float xv = bcast_lane(xcur, r);
                acc = fmaf(wih, xv, bias);
            } else {
                acc = 0.0f;
            }
            #pragma unroll
            for (int k = 0; k < 16; ++k) {
                float hj = bcast_lane(h, 4 * k + wv);
                acc = fmaf(w_sub[k], hj, acc);
            }

            const int p = r & 1;              // parity double-buffer
            part[p][wv][lane] = acc;
            asm volatile("s_waitcnt lgkmcnt(0)" ::: "memory");  // partial committed
            __builtin_amdgcn_s_barrier();

            // combine exactly as (acc0+acc1)+(acc2+acc3); volatile pins the
            // reads after the barrier
            volatile const float* pv = &part[p][0][0];
            float a0 = pv[lane];
            float a1 = pv[64 + lane];
            float a2 = pv[128 + lane];
            float a3 = pv[192 + lane];
            float a  = (a0 + a1) + (a2 + a3);
            h = tanh_fast(a);
            if (wv == (r & 3)) hbuf[r * ROWSTRIDE + lane] = h;  // one writer/row
        }
        __syncthreads();   // hbuf complete; also drains the x prefetch (done by now)

        // fc head: row r of the chunk handled by wave r>>4, lane r&15
        // (same per-row math and per-row accumulation order as before)
        if (lane < 16) {
            const int row = wv * 16 + lane;
            const float4* rp = (const float4*)(hbuf + row * ROWSTRIDE);
            float d0 = 0.f, d1 = 0.f;
            #pragma unroll
            for (int q = 0; q < 16; ++q) {
                float4 hh = rp[q];
                float4 f0 = ((const float4*)fc_w)[q];          // uniform -> s_load
                float4 f1 = ((const float4*)(fc_w + HID))[q];
                d0 += hh.x * f0.x + hh.y * f0.y + hh.z * f0.z + hh.w * f0.w;
                d1 += hh.x * f1.x + hh.y * f1.y + hh.z * f1.z + hh.w * f1.w;
            }
            float sel = sigmoid_fast(d0 + fcb0);
            float sco = sigmoid_fast(d1 + fcb1);
            num = fmaf(sco, sel, num);
            den += sel;
        }
        __syncthreads();   // hbuf reads done before next chunk overwrites
    }

    // Re-create the original 64-lane shuffle tree bitwise: park per-row
    // accumulators in LDS (row-indexed), wave 0 reduces with the same tree.
    if (lane < 16) {
        rowred_n[wv * 16 + lane] = num;
        rowred_d[wv * 16 + lane] = den;
    }
    __syncthreads();
    if (wv == 0) {
        float n = rowred_n[lane];
        float d = rowred_d[lane];
        #pragma unroll
        for (int off = 32; off > 0; off >>= 1) {
            n += __shfl_down(n, off);
            d += __shfl_down(d, off);
        }
        if (lane == 0) out[b] = n / d;
    }
}

extern "C" void kernel_launch(void* const* d_in, const int* in_sizes, int n_in,
                              void* d_out, int out_size, void* d_ws, size_t ws_size,
                              hipStream_t stream) {
    const float* x    = (const float*)d_in[0];
    const float* W_ih = (const float*)d_in[1];
    const float* b_ih = (const float*)d_in[2];
    const float* W_hh = (const float*)d_in[3];
    const float* b_hh = (const float*)d_in[4];
    const float* fc_w = (const float*)d_in[5];
    const float* fc_b = (const float*)d_in[6];
    float* out = (float*)d_out;

    rnn_splitk4_kernel<<<BATCH, 256, 0, stream>>>(x, W_ih, b_ih, W_hh, b_hh,
                                                  fc_w, fc_b, out);
}

// Round 4
// 2079.219 us; speedup vs baseline: 1.4829x; 1.4829x over previous
//
#include <hip/hip_runtime.h>
#include <math.h>

#define BATCH 128
#define SLEN  8000
#define HID   64
#define CHUNK 64                  // steps per fc flush; 8000 = 125 * 64
#define NCHUNK (SLEN / CHUNK)     // 125
#define ROWSTRIDE 68              // floats; keeps b128 row reads conflict-free

__device__ __forceinline__ float fast_exp2(float x) { return __builtin_amdgcn_exp2f(x); }
__device__ __forceinline__ float fast_rcp(float x)  { return __builtin_amdgcn_rcpf(x); }

__device__ __forceinline__ float bcast_lane(float v, int lane) {
    return __int_as_float(__builtin_amdgcn_readlane(__float_as_int(v), lane));
}

// tanh(x) = sign(x) * (e - 1)/(e + 1), e = 2^(2|x|*log2 e)   (UNCHANGED - bitwise)
__device__ __forceinline__ float tanh_fast(float x) {
    float ax = fabsf(x);
    float z  = fminf(ax * 2.8853900817779268f, 30.0f);
    float e  = fast_exp2(z);
    float r  = (e - 1.0f) * fast_rcp(e + 1.0f);
    return x < 0.0f ? -r : r;
}

__device__ __forceinline__ float sigmoid_fast(float x) {
    float z = fminf(fmaxf(-x * 1.4426950408889634f, -60.0f), 60.0f);
    float e = fast_exp2(z);
    return fast_rcp(1.0f + e);
}

// HYBRID broadcast: per step, j=0..31 via v_readlane (issue-heavy, latency-free),
// j=32..63 via 8x ds_read_b128 broadcast reads of the h row written LAST step
// (issue-light, ~120cy latency hidden under the readlane/FMA phase).
// The h-row LDS write already exists for the fc head, so the broadcast source
// is free. Chain structure acc[j&3], ascending j per chain -> bitwise-identical.
__global__ __launch_bounds__(64) void rnn_hybrid_kernel(
    const float* __restrict__ x,      // [B, S]
    const float* __restrict__ W_ih,   // [H, 1]
    const float* __restrict__ b_ih,   // [H]
    const float* __restrict__ W_hh,   // [H, H]
    const float* __restrict__ b_hh,   // [H]
    const float* __restrict__ fc_w,   // [2, H]
    const float* __restrict__ fc_b,   // [2]
    float* __restrict__ out)          // [B]
{
    __shared__ float hbuf[CHUNK * ROWSTRIDE];   // 64 rows of h history

    const int lane = threadIdx.x;               // == hidden index i
    const int b    = blockIdx.x;
    const float* xrow = x + (size_t)b * SLEN;

    // Lane i holds W_hh row i: w[j] = W_hh[i][j]
    float w[HID];
    #pragma unroll
    for (int q = 0; q < 16; ++q) {
        float4 t = ((const float4*)(W_hh + lane * HID))[q];
        w[4*q+0] = t.x; w[4*q+1] = t.y; w[4*q+2] = t.z; w[4*q+3] = t.w;
    }
    const float wih  = W_ih[lane];
    const float bias = b_ih[lane] + b_hh[lane];
    const float fcb0 = fc_b[0], fcb1 = fc_b[1];

    float h = 0.0f;                 // distributed hidden state: lane i holds h[i]
    float num = 0.0f, den = 0.0f;

    // h_{-1} = 0 lives in row 63 (read by step r=0 of chunk 0)
    hbuf[63 * ROWSTRIDE + lane] = 0.0f;

    float xv_next = xrow[lane];     // chunk 0's x values (one per lane)

    #pragma unroll 1
    for (int c = 0; c < NCHUNK; ++c) {
        float xcur = xv_next;
        // prefetch next chunk's x (off critical path; clamp index for last chunk)
        int nidx = (c + 1 < NCHUNK) ? (c + 1) * CHUNK + lane : lane;
        xv_next = xrow[nidx];

        #pragma unroll 4
        for (int r = 0; r < CHUNK; ++r) {
            // ---- phase 0: issue LDS broadcast reads for j=32..63 EARLY ----
            // (previous step's h row; in-order DS pipe makes the RAW safe)
            const float4* hp = (const float4*)(hbuf + ((r + 63) & 63) * ROWSTRIDE);
            float4 hreg[8];
            #pragma unroll
            for (int q = 0; q < 8; ++q) hreg[q] = hp[q + 8];   // floats 32..63

            float xv = bcast_lane(xcur, r);          // x_t

            float acc[4];
            acc[0] = fmaf(wih, xv, bias);
            acc[1] = 0.0f; acc[2] = 0.0f; acc[3] = 0.0f;

            // ---- phase 1: j = 0..31 via readlane (fills the LDS latency) ----
            #pragma unroll
            for (int j = 0; j < 32; ++j) {
                float hj = bcast_lane(h, j);
                acc[j & 3] = fmaf(w[j], hj, acc[j & 3]);
            }

            // ---- phase 2: j = 32..63 from the LDS broadcast values ----
            // hreg[q].x = h_prev[32+4q] ... matches w[32+4q+k], chain k = (j&3)
            #pragma unroll
            for (int q = 0; q < 8; ++q) {
                acc[0] = fmaf(w[32 + 4*q + 0], hreg[q].x, acc[0]);
                acc[1] = fmaf(w[32 + 4*q + 1], hreg[q].y, acc[1]);
                acc[2] = fmaf(w[32 + 4*q + 2], hreg[q].z, acc[2]);
                acc[3] = fmaf(w[32 + 4*q + 3], hreg[q].w, acc[3]);
            }

            float a = (acc[0] + acc[1]) + (acc[2] + acc[3]);
            h = tanh_fast(a);
            hbuf[r * ROWSTRIDE + lane] = h;   // feeds step r+1 (j>=32) AND fc head
        }
        __syncthreads();   // single wave -> lgkmcnt drain only

        // fc head for the chunk: lane processes row `lane` (1 timestep per lane)
        {
            const float4* rp = (const float4*)(hbuf + lane * ROWSTRIDE);
            float d0 = 0.f, d1 = 0.f;
            #pragma unroll
            for (int q = 0; q < 16; ++q) {
                float4 hh = rp[q];
                float4 f0 = ((const float4*)fc_w)[q];          // uniform -> s_load
                float4 f1 = ((const float4*)(fc_w + HID))[q];
                d0 += hh.x * f0.x + hh.y * f0.y + hh.z * f0.z + hh.w * f0.w;
                d1 += hh.x * f1.x + hh.y * f1.y + hh.z * f1.z + hh.w * f1.w;
            }
            float sel = sigmoid_fast(d0 + fcb0);
            float sco = sigmoid_fast(d1 + fcb1);
            num = fmaf(sco, sel, num);
            den += sel;
        }
        __syncthreads();   // hbuf reads done before next chunk overwrites
    }

    // Final cross-lane reduction of (num, den)
    #pragma unroll
    for (int off = 32; off > 0; off >>= 1) {
        num += __shfl_down(num, off);
        den += __shfl_down(den, off);
    }
    if (lane == 0) out[b] = num / den;
}

extern "C" void kernel_launch(void* const* d_in, const int* in_sizes, int n_in,
                              void* d_out, int out_size, void* d_ws, size_t ws_size,
                              hipStream_t stream) {
    const float* x    = (const float*)d_in[0];
    const float* W_ih = (const float*)d_in[1];
    const float* b_ih = (const float*)d_in[2];
    const float* W_hh = (const float*)d_in[3];
    const float* b_hh = (const float*)d_in[4];
    const float* fc_w = (const float*)d_in[5];
    const float* fc_b = (const float*)d_in[6];
    float* out = (float*)d_out;

    rnn_hybrid_kernel<<<BATCH, 64, 0, stream>>>(x, W_ih, b_ih, W_hh, b_hh,
                                                fc_w, fc_b, out);
}

// Round 5
// 1844.907 us; speedup vs baseline: 1.6712x; 1.1270x over previous
//
#include <hip/hip_runtime.h>
#include <math.h>

#define BATCH 128
#define SLEN  8000
#define HID   64
#define CHUNK 64                  // steps per fc flush; 8000 = 125 * 64
#define NCHUNK (SLEN / CHUNK)     // 125
#define ROWSTRIDE 68              // floats; even -> float2-aligned, b128-conflict-free

__device__ __forceinline__ float fast_exp2(float x) { return __builtin_amdgcn_exp2f(x); }
__device__ __forceinline__ float fast_rcp(float x)  { return __builtin_amdgcn_rcpf(x); }

__device__ __forceinline__ float bcast_lane(float v, int lane) {
    return __int_as_float(__builtin_amdgcn_readlane(__float_as_int(v), lane));
}

// tanh(x) = sign(x) * (e - 1)/(e + 1), e = 2^(2|x|*log2 e)   (UNCHANGED - bitwise)
__device__ __forceinline__ float tanh_fast(float x) {
    float ax = fabsf(x);
    float z  = fminf(ax * 2.8853900817779268f, 30.0f);
    float e  = fast_exp2(z);
    float r  = (e - 1.0f) * fast_rcp(e + 1.0f);
    return x < 0.0f ? -r : r;
}

__device__ __forceinline__ float sigmoid_fast(float x) {
    float z = fminf(fmaxf(-x * 1.4426950408889634f, -60.0f), 60.0f);
    float e = fast_exp2(z);
    return fast_rcp(1.0f + e);
}

// Solo-wave issue cadence is ~4 cyc/instr (fit of rounds 0/1/4), so the lever is
// INSTRUCTION COUNT on the serial path. v_pk_fma_f32 does 2 fp32 FMAs per
// instruction (exact IEEE fma per half -> bitwise-identical chains).
//   j<32 : 2x v_readlane into s[60:61] + 1x v_pk_fma_f32   (48 instrs vs 64)
//   j>=32: h pairs from prev-step LDS row (VGPR pairs) + v_pk_fma_f32 (16 + reads)
// LDS reads issue first; their latency hides under the 48-instr readlane phase.

// j<32 section: SGPR-pair broadcast + packed FMA. Lane indices are literals.
// VALU->VALU SGPR RAW is hardware-interlocked; s[60:61] declared clobbered.
#define PK_RL(J0, J1, ACC, WPK)                                             \
    asm volatile("v_readlane_b32 s60, %1, " #J0 "\n\t"                      \
                 "v_readlane_b32 s61, %1, " #J1 "\n\t"                      \
                 "v_pk_fma_f32 %0, %2, s[60:61], %0"                        \
                 : "+v"(ACC) : "v"(h), "v"(WPK) : "s60", "s61")

// j>=32 section: both operands VGPR pairs
#define PK_V(ACC, WPK, HPK)                                                 \
    asm volatile("v_pk_fma_f32 %0, %1, %2, %0"                              \
                 : "+v"(ACC) : "v"(WPK), "v"(HPK))

__global__ __launch_bounds__(64) void rnn_pkfma_kernel(
    const float* __restrict__ x,      // [B, S]
    const float* __restrict__ W_ih,   // [H, 1]
    const float* __restrict__ b_ih,   // [H]
    const float* __restrict__ W_hh,   // [H, H]
    const float* __restrict__ b_hh,   // [H]
    const float* __restrict__ fc_w,   // [2, H]
    const float* __restrict__ fc_b,   // [2]
    float* __restrict__ out)          // [B]
{
    __shared__ float hbuf[CHUNK * ROWSTRIDE];   // 64 rows of h history

    const int lane = threadIdx.x;               // == hidden index i
    const int b    = blockIdx.x;
    const float* xrow = x + (size_t)b * SLEN;

    // Lane i holds W_hh row i, packed as float2 pairs:
    //  wpk[2q]  = (w[4q],   w[4q+1])   -> a01 chain pair   (j < 32: q=0..7)
    //  wpk[2q+1]= (w[4q+2], w[4q+3])   -> a23 chain pair
    //  wpkh     = same for j >= 32
    float2 wpk[16], wpkh[16];
    #pragma unroll
    for (int q = 0; q < 8; ++q) {
        float4 t = ((const float4*)(W_hh + lane * HID))[q];
        wpk[2*q]   = make_float2(t.x, t.y);
        wpk[2*q+1] = make_float2(t.z, t.w);
    }
    #pragma unroll
    for (int q = 0; q < 8; ++q) {
        float4 t = ((const float4*)(W_hh + lane * HID))[8 + q];
        wpkh[2*q]   = make_float2(t.x, t.y);
        wpkh[2*q+1] = make_float2(t.z, t.w);
    }
    const float wih  = W_ih[lane];
    const float bias = b_ih[lane] + b_hh[lane];
    const float fcb0 = fc_b[0], fcb1 = fc_b[1];

    float h = 0.0f;                 // distributed hidden state: lane i holds h[i]
    float num = 0.0f, den = 0.0f;

    // h_{-1} = 0 lives in row 63 (read by step r=0 of chunk 0)
    hbuf[63 * ROWSTRIDE + lane] = 0.0f;

    float xv_next = xrow[lane];     // chunk 0's x values (one per lane)

    #pragma unroll 1
    for (int c = 0; c < NCHUNK; ++c) {
        float xcur = xv_next;
        // prefetch next chunk's x (off critical path; clamp index for last chunk)
        int nidx = (c + 1 < NCHUNK) ? (c + 1) * CHUNK + lane : lane;
        xv_next = xrow[nidx];

        #pragma unroll 4
        for (int r = 0; r < CHUNK; ++r) {
            // ---- issue LDS broadcast reads for j=32..63 EARLY (prev h row) ----
            const float2* hp2 = (const float2*)(hbuf + ((r + 63) & 63) * ROWSTRIDE);
            float2 hh[16];
            #pragma unroll
            for (int q = 0; q < 16; ++q) hh[q] = hp2[16 + q];  // floats 32..63

            float xv = bcast_lane(xcur, r);          // x_t

            // a01 = (acc0, acc1) chains, a23 = (acc2, acc3) chains — exact
            // same chain membership and in-chain order as the scalar version.
            float2 a01 = make_float2(fmaf(wih, xv, bias), 0.0f);
            float2 a23 = make_float2(0.0f, 0.0f);

            // ---- j = 0..31 via readlane SGPR pairs (fills the LDS latency) ----
            PK_RL( 0,  1, a01, wpk[0]);  PK_RL( 2,  3, a23, wpk[1]);
            PK_RL( 4,  5, a01, wpk[2]);  PK_RL( 6,  7, a23, wpk[3]);
            PK_RL( 8,  9, a01, wpk[4]);  PK_RL(10, 11, a23, wpk[5]);
            PK_RL(12, 13, a01, wpk[6]);  PK_RL(14, 15, a23, wpk[7]);
            PK_RL(16, 17, a01, wpk[8]);  PK_RL(18, 19, a23, wpk[9]);
            PK_RL(20, 21, a01, wpk[10]); PK_RL(22, 23, a23, wpk[11]);
            PK_RL(24, 25, a01, wpk[12]); PK_RL(26, 27, a23, wpk[13]);
            PK_RL(28, 29, a01, wpk[14]); PK_RL(30, 31, a23, wpk[15]);

            // ---- j = 32..63 from LDS broadcast pairs ----
            #pragma unroll
            for (int q = 0; q < 8; ++q) {
                PK_V(a01, wpkh[2*q],   hh[2*q]);     // j = 32+4q, 33+4q
                PK_V(a23, wpkh[2*q+1], hh[2*q+1]);   // j = 34+4q, 35+4q
            }

            float a = (a01.x + a01.y) + (a23.x + a23.y);
            h = tanh_fast(a);
            hbuf[r * ROWSTRIDE + lane] = h;   // feeds step r+1 (j>=32) AND fc head
        }
        __syncthreads();   // single wave -> lgkmcnt drain only

        // fc head for the chunk: lane processes row `lane` (1 timestep per lane)
        {
            const float4* rp = (const float4*)(hbuf + lane * ROWSTRIDE);
            float d0 = 0.f, d1 = 0.f;
            #pragma unroll
            for (int q = 0; q < 16; ++q) {
                float4 hv = rp[q];
                float4 f0 = ((const float4*)fc_w)[q];          // uniform -> s_load
                float4 f1 = ((const float4*)(fc_w + HID))[q];
                d0 += hv.x * f0.x + hv.y * f0.y + hv.z * f0.z + hv.w * f0.w;
                d1 += hv.x * f1.x + hv.y * f1.y + hv.z * f1.z + hv.w * f1.w;
            }
            float sel = sigmoid_fast(d0 + fcb0);
            float sco = sigmoid_fast(d1 + fcb1);
            num = fmaf(sco, sel, num);
            den += sel;
        }
        __syncthreads();   // hbuf reads done before next chunk overwrites
    }

    // Final cross-lane reduction of (num, den)
    #pragma unroll
    for (int off = 32; off > 0; off >>= 1) {
        num += __shfl_down(num, off);
        den += __shfl_down(den, off);
    }
    if (lane == 0) out[b] = num / den;
}

extern "C" void kernel_launch(void* const* d_in, const int* in_sizes, int n_in,
                              void* d_out, int out_size, void* d_ws, size_t ws_size,
                              hipStream_t stream) {
    const float* x    = (const float*)d_in[0];
    const float* W_ih = (const float*)d_in[1];
    const float* b_ih = (const float*)d_in[2];
    const float* W_hh = (const float*)d_in[3];
    const float* b_hh = (const float*)d_in[4];
    const float* fc_w = (const float*)d_in[5];
    const float* fc_b = (const float*)d_in[6];
    float* out = (float*)d_out;

    rnn_pkfma_kernel<<<BATCH, 64, 0, stream>>>(x, W_ih, b_ih, W_hh, b_hh,
                                               fc_w, fc_b, out);
}